// Round 26
// baseline (4040.593 us; speedup 1.0000x reference)
//
#include <hip/hip_runtime.h>
#include <cstdint>
#include <cstddef>

#define EPSF 1e-5f

typedef unsigned short u16;
typedef __attribute__((ext_vector_type(8))) short short8v;
typedef __attribute__((ext_vector_type(4))) float f32x4;

static __device__ __forceinline__ u16 f2bf(float f) {
  union { float f; unsigned u; } v; v.f = f;
  unsigned r = v.u + 0x7fffu + ((v.u >> 16) & 1u);
  return (u16)(r >> 16);
}
static __device__ __forceinline__ float bf2f(u16 h) {
  union { unsigned u; float f; } v; v.u = ((unsigned)h) << 16;
  return v.f;
}

// ---------------- weight prep ----------------
__global__ void k_wconv(const float* __restrict__ src, u16* __restrict__ dst) {
  int i = blockIdx.x * 256 + threadIdx.x;
  if (i >= 4 * 256 * 256 * 5) return;
  int k = i % 5, r = i / 5;
  int ci = r & 255; r >>= 8;
  int co = r & 255; int l = r >> 8;
  dst[(((size_t)l * 256 + co) * 5 + k) * 256 + ci] = f2bf(src[i]);
}
__global__ void k_wti(const float* __restrict__ src, u16* __restrict__ dst) {
  int i = blockIdx.x * 256 + threadIdx.x;
  if (i >= 8 * 1288 * 256) return;
  int k = i & 255; int r = i >> 8;
  int n = r % 1288; int l = r / 1288;
  dst[i] = f2bf(src[((size_t)l * 256 + k) * 1288 + n]);
}
__global__ void k_wto(const float* __restrict__ src, u16* __restrict__ dst) {
  int i = blockIdx.x * 256 + threadIdx.x;
  if (i >= 8 * 256 * 512) return;
  int k = i & 511; int r = i >> 9;
  int n = r & 255; int l = r >> 8;
  dst[i] = f2bf(src[((size_t)l * 512 + k) * 256 + n]);
}

// ---------------- patch embed -> [b][L][256] bf16
__global__ __launch_bounds__(256) void k_patchm(const float* __restrict__ x, const float* __restrict__ pw,
                                                const float* __restrict__ pb, u16* __restrict__ outb) {
  __shared__ float xs[8][64];
  const int l0 = blockIdx.x * 64;
  const int b = blockIdx.y;
  const int tid = threadIdx.x;
  const float* xb = x + (size_t)b * 8 * 12288;
  for (int q = tid; q < 512; q += 256) {
    int p = q >> 6, ll = q & 63;
    xs[p][ll] = xb[(size_t)p * 12288 + l0 + ll];
  }
  __syncthreads();
  float pwr[8];
#pragma unroll
  for (int p = 0; p < 8; ++p) pwr[p] = pw[tid * 8 + p];
  const float bias = pb[tid];
  u16* ob = outb + ((size_t)b * 12288 + l0) * 256 + tid;
  for (int ll = 0; ll < 64; ++ll) {
    float acc = bias;
#pragma unroll
    for (int p = 0; p < 8; ++p) acc += xs[p][ll] * pwr[p];
    ob[(size_t)ll * 256] = f2bf(acc);
  }
}

// ---------------- MFMA conv1d (256->256, K=5 causal) + BN + ReLU, [L][C] bf16 (64-wide)
// P2==1: fused maxpool k=2 over L (output L/2 rows)
template <int P2>
__global__ __launch_bounds__(256) void k_convm(const u16* __restrict__ in, const u16* __restrict__ wbf,
                                               const float* __restrict__ cbias, const float* __restrict__ bng,
                                               const float* __restrict__ bnb, u16* __restrict__ outb, int L) {
  __shared__ u16 Xs[132 * 40];
  __shared__ u16 Ws[64 * 168];
  const int l0 = blockIdx.x * 128;
  const int co0 = blockIdx.y * 64;
  const int b = blockIdx.z;
  const int tid = threadIdx.x;
  const int w = tid >> 6, l = tid & 63;
  const int mhalf = (w >> 1) * 64, nhalf = (w & 1) * 32;
  const u16* inb = in + (size_t)b * L * 256;
  f32x4 acc[4][2] = {};
  for (int ci0 = 0; ci0 < 256; ci0 += 32) {
    __syncthreads();
    for (int q = tid; q < 528; q += 256) {
      int row = q >> 2, coff = (q & 3) * 8;
      int gl = l0 - 4 + row;
      short8v v = {};
      if (gl >= 0) v = *(const short8v*)(inb + (size_t)gl * 256 + ci0 + coff);
      *(short8v*)(Xs + row * 40 + coff) = v;
    }
    for (int q = tid; q < 1280; q += 256) {
      int co = q / 20, rem = q % 20, k = rem >> 2, coff = (rem & 3) * 8;
      *(short8v*)(Ws + co * 168 + k * 32 + coff) =
          *(const short8v*)(wbf + ((size_t)(co0 + co) * 5 + k) * 256 + ci0 + coff);
    }
    __syncthreads();
    const int koff = (l >> 4) * 8;
    const int arow = mhalf + (l & 15);
    const int bro0 = (nhalf + (l & 15)) * 168;
    const int bro1 = (nhalf + 16 + (l & 15)) * 168;
#pragma unroll
    for (int k = 0; k < 5; ++k) {
      short8v b0 = *(const short8v*)(Ws + bro0 + k * 32 + koff);
      short8v b1 = *(const short8v*)(Ws + bro1 + k * 32 + koff);
#pragma unroll
      for (int mi = 0; mi < 4; ++mi) {
        short8v a = *(const short8v*)(Xs + (arow + mi * 16 + k) * 40 + koff);
        acc[mi][0] = __builtin_amdgcn_mfma_f32_16x16x32_bf16(a, b0, acc[mi][0], 0, 0, 0);
        acc[mi][1] = __builtin_amdgcn_mfma_f32_16x16x32_bf16(a, b1, acc[mi][1], 0, 0, 0);
      }
    }
  }
  const float scn = rsqrtf(1.f + EPSF);
  if constexpr (!P2) {
    u16* outbb = outb + (size_t)b * L * 256;
#pragma unroll
    for (int ni = 0; ni < 2; ++ni) {
      int co = co0 + nhalf + ni * 16 + (l & 15);
      float alpha = bng[co] * scn;
      float beta = cbias[co] * alpha + bnb[co];
#pragma unroll
      for (int mi = 0; mi < 4; ++mi)
#pragma unroll
        for (int r = 0; r < 4; ++r) {
          int row = l0 + mhalf + mi * 16 + (l >> 4) * 4 + r;
          float v = acc[mi][ni][r] * alpha + beta;
          outbb[(size_t)row * 256 + co] = f2bf(fmaxf(v, 0.f));
        }
    }
  } else {
    const int Lo = L >> 1;
    u16* outbb = outb + (size_t)b * Lo * 256;
#pragma unroll
    for (int ni = 0; ni < 2; ++ni) {
      int co = co0 + nhalf + ni * 16 + (l & 15);
      float alpha = bng[co] * scn;
      float beta = cbias[co] * alpha + bnb[co];
#pragma unroll
      for (int mi = 0; mi < 4; ++mi) {
        int base = l0 + mhalf + mi * 16 + (l >> 4) * 4;  // even
        float vv[4];
#pragma unroll
        for (int r = 0; r < 4; ++r) vv[r] = fmaxf(acc[mi][ni][r] * alpha + beta, 0.f);
#pragma unroll
        for (int pr = 0; pr < 2; ++pr) {
          float m2 = fmaxf(vv[2 * pr], vv[2 * pr + 1]);
          int orow = (base >> 1) + pr;
          outbb[(size_t)orow * 256 + co] = f2bf(m2);
        }
      }
    }
  }
}

// ---------------- maxpool over L dim, [L][C] bf16 (k=3)
__global__ void k_mpb(const u16* __restrict__ in, u16* __restrict__ out, int Lout, int kp, size_t total) {
  size_t i = (size_t)blockIdx.x * 256 + threadIdx.x;
  if (i >= total) return;
  size_t c = i & 255;
  size_t rest = i >> 8;
  size_t lo = rest % (size_t)Lout;
  size_t b = rest / (size_t)Lout;
  const u16* p = in + (b * (size_t)Lout * kp + lo * kp) * 256 + c;
  float m = bf2f(p[0]);
  for (int j = 1; j < kp; ++j) m = fmaxf(m, bf2f(p[(size_t)j * 256]));
  out[i] = f2bf(m);
}

// ---------------- assemble u rows 0..2048 (f32 + bf16) ; row0 = cls+pos
__global__ __launch_bounds__(256) void k_asmb(const u16* __restrict__ in, const float* __restrict__ pos,
                                              const float* __restrict__ cls, float* __restrict__ uc,
                                              u16* __restrict__ ubc) {
  int t = blockIdx.x;
  int b = blockIdx.y;
  int e = threadIdx.x;
  float v;
  if (t == 0)
    v = cls[e] + pos[e];
  else
    v = bf2f(in[((size_t)b * 2048 + (t - 1)) * 256 + e]) + pos[(size_t)t * 256 + e];
  size_t o = ((size_t)b * 2049 + t) * 256 + e;
  uc[o] = v;
  ubc[o] = f2bf(v);
}

// ---------------- MFMA GEMM: A_bf[M,K] @ BT_bf[N,K]; K%32==0
// MODE 0 (in-proj): n<1280 -> zxb bf16 [M][1280]; n>=1280 -> dtr f32 [M][8]
// MODE 1 (out-proj): C[M,N] += acc (f32) and ubf bf16 copy
template <int MODE>
__global__ __launch_bounds__(256) void k_gemmm(const u16* __restrict__ A, const u16* __restrict__ BT,
                                               u16* __restrict__ OB, float* __restrict__ DT,
                                               float* __restrict__ C, u16* __restrict__ ubf,
                                               int M, int N, int K) {
  __shared__ u16 As[128 * 40];
  __shared__ u16 Bs[64 * 40];
  const int n0 = blockIdx.x * 64;
  const int m0 = blockIdx.y * 128;
  const int tid = threadIdx.x;
  const int w = tid >> 6, l = tid & 63;
  const int mhalf = (w >> 1) * 64, nhalf = (w & 1) * 32;
  f32x4 acc[4][2] = {};
  for (int k0 = 0; k0 < K; k0 += 32) {
    __syncthreads();
    for (int q = tid; q < 512; q += 256) {
      int row = q >> 2, koff = (q & 3) * 8;
      short8v v = {};
      if (m0 + row < M) v = *(const short8v*)(A + (size_t)(m0 + row) * K + k0 + koff);
      *(short8v*)(As + row * 40 + koff) = v;
    }
    {
      int row = tid >> 2, koff = (tid & 3) * 8;
      short8v v = {};
      if (n0 + row < N) v = *(const short8v*)(BT + (size_t)(n0 + row) * K + k0 + koff);
      *(short8v*)(Bs + row * 40 + koff) = v;
    }
    __syncthreads();
    const int koff = (l >> 4) * 8;
    short8v b0 = *(const short8v*)(Bs + (nhalf + (l & 15)) * 40 + koff);
    short8v b1 = *(const short8v*)(Bs + (nhalf + 16 + (l & 15)) * 40 + koff);
#pragma unroll
    for (int mi = 0; mi < 4; ++mi) {
      short8v a = *(const short8v*)(As + (mhalf + mi * 16 + (l & 15)) * 40 + koff);
      acc[mi][0] = __builtin_amdgcn_mfma_f32_16x16x32_bf16(a, b0, acc[mi][0], 0, 0, 0);
      acc[mi][1] = __builtin_amdgcn_mfma_f32_16x16x32_bf16(a, b1, acc[mi][1], 0, 0, 0);
    }
  }
#pragma unroll
  for (int mi = 0; mi < 4; ++mi)
#pragma unroll
    for (int r = 0; r < 4; ++r) {
      int m = m0 + mhalf + mi * 16 + (l >> 4) * 4 + r;
      if (m >= M) continue;
#pragma unroll
      for (int ni = 0; ni < 2; ++ni) {
        int n = n0 + nhalf + ni * 16 + (l & 15);
        if (n >= N) continue;
        float v = acc[mi][ni][r];
        if constexpr (MODE == 0) {
          if (n < 1280) OB[(size_t)m * 1280 + n] = f2bf(v);
          else DT[(size_t)m * 8 + (n - 1280)] = v;
        } else {
          float vv = C[(size_t)m * N + n] + v;
          C[(size_t)m * N + n] = vv;
          ubf[(size_t)m * N + n] = f2bf(vv);
        }
      }
    }
}

// ---------------- depthwise causal conv K=4 + silu (bf16 in/out), t-tile 16 ; bx==3: dt/ld
__global__ __launch_bounds__(256) void k_dw(const u16* __restrict__ zxb, const float* __restrict__ dtr,
                                            const float* __restrict__ cw, const float* __restrict__ cb,
                                            const float* __restrict__ dtbias, const float* __restrict__ al,
                                            u16* __restrict__ xBCb, float* __restrict__ dtb,
                                            float* __restrict__ ldb) {
  const int bx = blockIdx.x;
  const int t0 = blockIdx.y * 16;
  const int b = blockIdx.z;
  if (bx == 3) {
    int h = threadIdx.x & 7, ro = threadIdx.x >> 3;
    if (ro < 16) {
      int r = t0 + ro;
      if (r < 2049) {
        float v = dtr[((size_t)b * 2049 + r) * 8 + h] + dtbias[h];
        float d = (v > 20.f) ? v : log1pf(expf(v));
        size_t o = ((size_t)b * 2049 + r) * 8 + h;
        dtb[o] = d;
        ldb[o] = -expf(al[h]) * d;
      }
    }
    return;
  }
  int c = bx * 256 + threadIdx.x;
  const u16* col = zxb + ((size_t)b * 2049) * 1280 + 512 + c;
  float cw0 = cw[c * 4 + 0], cw1 = cw[c * 4 + 1], cw2 = cw[c * 4 + 2], cw3 = cw[c * 4 + 3];
  const float bias = cb[c];
  float w0 = 0.f, w1 = 0.f, w2 = 0.f;
  if (t0 - 3 >= 0) w0 = bf2f(col[(size_t)(t0 - 3) * 1280]);
  if (t0 - 2 >= 0) w1 = bf2f(col[(size_t)(t0 - 2) * 1280]);
  if (t0 - 1 >= 0) w2 = bf2f(col[(size_t)(t0 - 1) * 1280]);
  int tend = t0 + 16; if (tend > 2049) tend = 2049;
  u16* ob = xBCb + ((size_t)b * 2049) * 768 + c;
  for (int t = t0; t < tend; ++t) {
    float v = bf2f(col[(size_t)t * 1280]);
    float acc = bias + w0 * cw0 + w1 * cw1 + w2 * cw2 + v * cw3;
    float sig = 1.f / (1.f + expf(-acc));
    ob[(size_t)t * 768] = f2bf(acc * sig);
    w0 = w1; w1 = w2; w2 = v;
  }
}

// ================= MFMA chunked SSD (Q=128, 17 chunks over L=2049) =================
// G = C·Bᵀ is HEAD-INDEPENDENT: compute once per (c,b), store f32 (bit-identical reuse)
__global__ __launch_bounds__(256) void k_ssd_g(const u16* __restrict__ xBCb,
                                               float* __restrict__ G) {
  const int L = 2049;
  const int c = blockIdx.x, b = blockIdx.y;
  const int tid = threadIdx.x;
  const int w = tid >> 6, l = tid & 63;
  const int t0 = c * 128;
  int qc = L - t0; if (qc > 128) qc = 128;

  __shared__ u16 R1[128 * 136];  // Bs
  __shared__ u16 R2[128 * 136];  // Cs

  const u16* xb = xBCb + ((size_t)b * L) * 768;
  for (int q = tid; q < 2048; q += 256) {
    int row = q >> 4, off = (q & 15) * 8;
    short8v vb = {}, vc = {};
    if (row < qc) {
      const u16* src = xb + (size_t)(t0 + row) * 768;
      vb = *(const short8v*)(src + 512 + off);
      vc = *(const short8v*)(src + 640 + off);
    }
    *(short8v*)(R1 + row * 136 + off) = vb;
    *(short8v*)(R2 + row * 136 + off) = vc;
  }
  __syncthreads();

  const int wm = (w >> 1) * 64, wn = (w & 1) * 64;
  if (wm < wn) return;  // upper-right quadrant never read (s>t)
  f32x4 g[4][4] = {};
#pragma unroll
  for (int ks = 0; ks < 4; ++ks) {
    const int koff = ks * 32 + (l >> 4) * 8;
    short8v bf[4];
#pragma unroll
    for (int ni = 0; ni < 4; ++ni)
      bf[ni] = *(const short8v*)(R1 + (wn + ni * 16 + (l & 15)) * 136 + koff);
#pragma unroll
    for (int mi = 0; mi < 4; ++mi) {
      short8v a = *(const short8v*)(R2 + (wm + mi * 16 + (l & 15)) * 136 + koff);
#pragma unroll
      for (int ni = 0; ni < 4; ++ni)
        g[mi][ni] = __builtin_amdgcn_mfma_f32_16x16x32_bf16(a, bf[ni], g[mi][ni], 0, 0, 0);
    }
  }
  float* Gp = G + ((size_t)b * 17 + c) * 16384;
#pragma unroll
  for (int mi = 0; mi < 4; ++mi)
#pragma unroll
    for (int r = 0; r < 4; ++r) {
      int t = wm + mi * 16 + (l >> 4) * 4 + r;
#pragma unroll
      for (int ni = 0; ni < 4; ++ni) {
        int s = wn + ni * 16 + (l & 15);
        Gp[t * 128 + s] = g[mi][ni][r];
      }
    }
}

// intra per (c,h,b): Ms from global G -> Y=Ms@X (bf16) -> XW -> Sc=XW@BT (bf16)
__global__ __launch_bounds__(256) void k_ssd_intra(const u16* __restrict__ xBCb,
                                                   const float* __restrict__ dtg,
                                                   const float* __restrict__ ldg,
                                                   const float* __restrict__ G,
                                                   u16* __restrict__ ybuf,
                                                   u16* __restrict__ sc,
                                                   float* __restrict__ dtot) {
  const int L = 2049;
  const int c = blockIdx.x, h = blockIdx.y, b = blockIdx.z;
  const int tid = threadIdx.x;
  const int w = tid >> 6, l = tid & 63;
  const int t0 = c * 128;
  int qc = L - t0; if (qc > 128) qc = 128;

  __shared__ u16 R1[128 * 136];  // XT -> XW
  __shared__ u16 R2[128 * 136];  // Ms -> BT
  __shared__ float dt_s[128], Lc_s[128];

  const u16* xb = xBCb + ((size_t)b * L) * 768;

  if (tid < 64) {
    int i2 = tid * 2;
    float a0 = 0.f, a1 = 0.f, d0 = 0.f, d1 = 0.f;
    if (i2 < qc) { size_t r = ((size_t)b * L + t0 + i2) * 8 + h; a0 = ldg[r]; d0 = dtg[r]; }
    if (i2 + 1 < qc) { size_t r = ((size_t)b * L + t0 + i2 + 1) * 8 + h; a1 = ldg[r]; d1 = dtg[r]; }
    dt_s[i2] = d0; dt_s[i2 + 1] = d1;
    float v = a0 + a1;
#pragma unroll
    for (int dlt = 1; dlt < 64; dlt <<= 1) {
      float t = __shfl_up(v, dlt, 64);
      if (tid >= dlt) v += t;
    }
    Lc_s[i2 + 1] = v;
    Lc_s[i2] = v - a1;
  }

  // XT -> R1 (transposed [p][s])
  for (int q = tid; q < 1024; q += 256) {
    int s = q >> 3, pv = (q & 7) * 8;
    short8v v = {};
    if (s < qc) v = *(const short8v*)(xb + (size_t)(t0 + s) * 768 + h * 64 + pv);
#pragma unroll
    for (int j = 0; j < 8; ++j) R1[(pv + j) * 136 + s] = (u16)v[j];
  }
  __syncthreads();  // B1

  // Ms -> R2 from global G ; dtot
  const float* Gp = G + ((size_t)b * 17 + c) * 16384;
  const int wm = (w >> 1) * 64, wn = (w & 1) * 64;
#pragma unroll
  for (int mi = 0; mi < 4; ++mi)
#pragma unroll
    for (int r = 0; r < 4; ++r) {
      int t = wm + mi * 16 + (l >> 4) * 4 + r;
      float lct = Lc_s[t];
#pragma unroll
      for (int ni = 0; ni < 4; ++ni) {
        int s = wn + ni * 16 + (l & 15);
        float v = 0.f;
        if (s <= t) v = __expf(lct - Lc_s[s]) * dt_s[s] * Gp[t * 128 + s];
        R2[t * 136 + s] = f2bf(v);
      }
    }
  if (tid == 0) dtot[((size_t)b * 8 + h) * 17 + c] = __expf(Lc_s[qc - 1]);
  __syncthreads();  // B2

  // Y = Ms(R2) @ XT(R1)  (128×64, K=128) -> bf16
  {
    const int wmy = (w >> 1) * 64, wny = (w & 1) * 32;
    f32x4 ya[4][2] = {};
#pragma unroll
    for (int ks = 0; ks < 4; ++ks) {
      const int koff = ks * 32 + (l >> 4) * 8;
      short8v b0 = *(const short8v*)(R1 + (wny + (l & 15)) * 136 + koff);
      short8v b1 = *(const short8v*)(R1 + (wny + 16 + (l & 15)) * 136 + koff);
#pragma unroll
      for (int mi = 0; mi < 4; ++mi) {
        short8v a = *(const short8v*)(R2 + (wmy + mi * 16 + (l & 15)) * 136 + koff);
        ya[mi][0] = __builtin_amdgcn_mfma_f32_16x16x32_bf16(a, b0, ya[mi][0], 0, 0, 0);
        ya[mi][1] = __builtin_amdgcn_mfma_f32_16x16x32_bf16(a, b1, ya[mi][1], 0, 0, 0);
      }
    }
    u16* yb = ybuf + ((size_t)b * L + t0) * 512 + h * 64;
#pragma unroll
    for (int mi = 0; mi < 4; ++mi)
#pragma unroll
      for (int r = 0; r < 4; ++r) {
        int t = wmy + mi * 16 + (l >> 4) * 4 + r;
        if (t >= qc) continue;
#pragma unroll
        for (int ni = 0; ni < 2; ++ni) {
          int p = wny + ni * 16 + (l & 15);
          yb[(size_t)t * 512 + p] = f2bf(ya[mi][ni][r]);
        }
      }
  }
  __syncthreads();  // B3

  // fused state: XW in-place in R1 rows 0..63 ; BT -> R2
  {
    const float Lend = Lc_s[qc - 1];
    for (int q = tid; q < 8192; q += 256) {
      int p = q >> 7, s = q & 127;
      float w2 = __expf(Lend - Lc_s[s]) * dt_s[s];
      R1[p * 136 + s] = f2bf(bf2f(R1[p * 136 + s]) * w2);
    }
    for (int q = tid; q < 2048; q += 256) {
      int s = q >> 4, nv = (q & 15) * 8;
      short8v v = {};
      if (s < qc) v = *(const short8v*)(xb + (size_t)(t0 + s) * 768 + 512 + nv);
#pragma unroll
      for (int j = 0; j < 8; ++j) R2[(nv + j) * 136 + s] = (u16)v[j];
    }
  }
  __syncthreads();  // B4

  // Sc = XW(R1) @ BT(R2)  (64×128, K=128) -> bf16
  {
    const int wms = (w & 1) * 32, wns = (w >> 1) * 64;
    f32x4 sa[2][4] = {};
#pragma unroll
    for (int ks = 0; ks < 4; ++ks) {
      const int koff = ks * 32 + (l >> 4) * 8;
      short8v a0 = *(const short8v*)(R1 + (wms + (l & 15)) * 136 + koff);
      short8v a1 = *(const short8v*)(R1 + (wms + 16 + (l & 15)) * 136 + koff);
#pragma unroll
      for (int ni = 0; ni < 4; ++ni) {
        short8v bb = *(const short8v*)(R2 + (wns + ni * 16 + (l & 15)) * 136 + koff);
        sa[0][ni] = __builtin_amdgcn_mfma_f32_16x16x32_bf16(a0, bb, sa[0][ni], 0, 0, 0);
        sa[1][ni] = __builtin_amdgcn_mfma_f32_16x16x32_bf16(a1, bb, sa[1][ni], 0, 0, 0);
      }
    }
    u16* scp = sc + (((size_t)b * 8 + h) * 17 + c) * 8192;
#pragma unroll
    for (int mi = 0; mi < 2; ++mi)
#pragma unroll
      for (int r = 0; r < 4; ++r) {
        int p = wms + mi * 16 + (l >> 4) * 4 + r;
#pragma unroll
        for (int ni = 0; ni < 4; ++ni) {
          int n = wns + ni * 16 + (l & 15);
          scp[p * 128 + n] = f2bf(sa[mi][ni][r]);
        }
      }
  }
}

// scan over 17 chunks; sc bf16 storage, f32 register recurrence
__global__ __launch_bounds__(256) void k_ssd_scan(u16* __restrict__ sc, const float* __restrict__ dtot,
                                                  int nbh) {
  int gid = blockIdx.x * 256 + threadIdx.x;
  int bh = gid >> 13;
  if (bh >= nbh) return;
  int elem = gid & 8191;
  u16* base = sc + (size_t)bh * 17 * 8192 + elem;
  const float* dtp = dtot + (size_t)bh * 17;
  float hc = 0.f;
#pragma unroll
  for (int cc = 0; cc < 17; ++cc) {
    float D = dtp[cc];
    float v = bf2f(base[(size_t)cc * 8192]);
    base[(size_t)cc * 8192] = f2bf(hc);
    hc = hc * D + v;
  }
}

__global__ __launch_bounds__(256) void k_ssd_inter(const u16* __restrict__ xBCb,
                                                   const float* __restrict__ ldg,
                                                   const u16* __restrict__ sc,
                                                   const float* __restrict__ Dh,
                                                   u16* __restrict__ ybuf) {
  const int L = 2049;
  const int c = blockIdx.x, h = blockIdx.y, b = blockIdx.z;
  const int tid = threadIdx.x;
  const int w = tid >> 6, l = tid & 63;
  const int t0 = c * 128;
  int qc = L - t0; if (qc > 128) qc = 128;

  __shared__ u16 Cs[128 * 136];
  __shared__ u16 H0[64 * 136];
  __shared__ float Lc_s[128];

  const u16* xb = xBCb + ((size_t)b * L) * 768;

  if (tid < 64) {
    int i2 = tid * 2;
    float a0 = 0.f, a1 = 0.f;
    if (i2 < qc) a0 = ldg[((size_t)b * L + t0 + i2) * 8 + h];
    if (i2 + 1 < qc) a1 = ldg[((size_t)b * L + t0 + i2 + 1) * 8 + h];
    float v = a0 + a1;
#pragma unroll
    for (int dlt = 1; dlt < 64; dlt <<= 1) {
      float t = __shfl_up(v, dlt, 64);
      if (tid >= dlt) v += t;
    }
    Lc_s[i2 + 1] = v;
    Lc_s[i2] = v - a1;
  }
  for (int q = tid; q < 2048; q += 256) {
    int row = q >> 4, off = (q & 15) * 8;
    short8v vc = {};
    if (row < qc) vc = *(const short8v*)(xb + (size_t)(t0 + row) * 768 + 640 + off);
    *(short8v*)(Cs + row * 136 + off) = vc;
  }
  {
    const u16* hp = sc + (((size_t)b * 8 + h) * 17 + c) * 8192;
    for (int q = tid; q < 1024; q += 256) {
      int p = q >> 4, nv = (q & 15) * 8;
      *(short8v*)(H0 + p * 136 + nv) = *(const short8v*)(hp + p * 128 + nv);
    }
  }
  __syncthreads();

  const int wm = (w >> 1) * 64, wn = (w & 1) * 32;
  f32x4 acc[4][2] = {};
#pragma unroll
  for (int ks = 0; ks < 4; ++ks) {
    const int koff = ks * 32 + (l >> 4) * 8;
    short8v b0 = *(const short8v*)(H0 + (wn + (l & 15)) * 136 + koff);
    short8v b1 = *(const short8v*)(H0 + (wn + 16 + (l & 15)) * 136 + koff);
#pragma unroll
    for (int mi = 0; mi < 4; ++mi) {
      short8v a = *(const short8v*)(Cs + (wm + mi * 16 + (l & 15)) * 136 + koff);
      acc[mi][0] = __builtin_amdgcn_mfma_f32_16x16x32_bf16(a, b0, acc[mi][0], 0, 0, 0);
      acc[mi][1] = __builtin_amdgcn_mfma_f32_16x16x32_bf16(a, b1, acc[mi][1], 0, 0, 0);
    }
  }
  const float DD = Dh[h];
  u16* yb = ybuf + ((size_t)b * L + t0) * 512 + h * 64;
#pragma unroll
  for (int mi = 0; mi < 4; ++mi)
#pragma unroll
    for (int r = 0; r < 4; ++r) {
      int t = wm + mi * 16 + (l >> 4) * 4 + r;
      if (t >= qc) continue;
      float e = __expf(Lc_s[t]);
#pragma unroll
      for (int ni = 0; ni < 2; ++ni) {
        int p = wn + ni * 16 + (l & 15);
        float xs = bf2f(xb[(size_t)(t0 + t) * 768 + h * 64 + p]);
        float old = bf2f(yb[(size_t)t * 512 + p]);
        yb[(size_t)t * 512 + p] = f2bf(old + e * acc[mi][ni][r] + DD * xs);
      }
    }
}

// ---------------- y = y*silu(z); RMS-norm over 512; *norm_w ; write bf16 (y,z bf16)
__global__ __launch_bounds__(256) void k_gaterms(const u16* __restrict__ ybuf, const u16* __restrict__ zxb,
                                                 const float* __restrict__ nw, u16* __restrict__ y2,
                                                 int Mc) {
  int row = blockIdx.x * 4 + (threadIdx.x >> 6);
  if (row >= Mc) return;
  int lane = threadIdx.x & 63;
  const u16* yr = ybuf + (size_t)row * 512 + lane * 8;
  const u16* zr = zxb + (size_t)row * 1280 + lane * 8;
  short8v yv8 = *(const short8v*)yr;
  short8v zv8 = *(const short8v*)zr;
  float g[8];
  float ss = 0.f;
#pragma unroll
  for (int j = 0; j < 8; ++j) {
    float yv = bf2f((u16)yv8[j]);
    float zv = bf2f((u16)zv8[j]);
    float sig = 1.f / (1.f + expf(-zv));
    float gg = yv * zv * sig;
    g[j] = gg;
    ss += gg * gg;
  }
#pragma unroll
  for (int off = 32; off > 0; off >>= 1) ss += __shfl_xor(ss, off);
  float r = rsqrtf(ss * (1.f / 512.f) + EPSF);
#pragma unroll
  for (int j = 0; j < 8; ++j)
    y2[(size_t)row * 512 + lane * 8 + j] = f2bf(g[j] * r * nw[lane * 8 + j]);
}

// ---------------- final LayerNorm over E=256 for rows t=1..2048 (wave per row)
__global__ __launch_bounds__(256) void k_ln(const float* __restrict__ u, const float* __restrict__ g,
                                            const float* __restrict__ bb, float* __restrict__ out) {
  int rid = blockIdx.x * 4 + (threadIdx.x >> 6);
  int lane = threadIdx.x & 63;
  int b = rid >> 11;
  int t = (rid & 2047) + 1;
  const float* ur = u + ((size_t)b * 2049 + t) * 256 + lane * 4;
  float v[4];
  float s1 = 0.f, s2 = 0.f;
#pragma unroll
  for (int j = 0; j < 4; ++j) {
    v[j] = ur[j];
    s1 += v[j];
    s2 += v[j] * v[j];
  }
#pragma unroll
  for (int off = 32; off > 0; off >>= 1) {
    s1 += __shfl_xor(s1, off);
    s2 += __shfl_xor(s2, off);
  }
  float mu = s1 * (1.f / 256.f);
  float var = s2 * (1.f / 256.f) - mu * mu;
  float rs = rsqrtf(var + EPSF);
  float* orow = out + ((size_t)b * 2048 + (t - 1)) * 256 + lane * 4;
#pragma unroll
  for (int j = 0; j < 4; ++j) orow[j] = (v[j] - mu) * rs * g[lane * 4 + j] + bb[lane * 4 + j];
}

// ---------------- masked pool partials (32 chunks of 64 rows)
__global__ __launch_bounds__(256) void k_pp(const float* __restrict__ hln, const int* __restrict__ idx,
                                            float* __restrict__ part) {
  int ch = blockIdx.x;
  int b = blockIdx.y;
  int e = threadIdx.x;
  int agg = idx[b] / 6;
  int t0 = ch * 64;
  int tend = agg + 1 - t0;
  if (tend > 64) tend = 64;
  float s = 0.f;
  for (int i = 0; i < tend; ++i) s += hln[((size_t)b * 2048 + t0 + i) * 256 + e];
  part[((size_t)b * 32 + ch) * 256 + e] = s;
}

// ---------------- pooled @ fc_w + fc_b
__global__ __launch_bounds__(256) void k_fc(const float* __restrict__ part, const int* __restrict__ idx,
                                            const float* __restrict__ fw, const float* __restrict__ fb,
                                            float* __restrict__ out) {
  __shared__ float pooled[256];
  int b = blockIdx.x;
  int tid = threadIdx.x;
  float s = 0.f;
#pragma unroll
  for (int ch = 0; ch < 32; ++ch) s += part[((size_t)b * 32 + ch) * 256 + tid];
  pooled[tid] = s;
  __syncthreads();
  if (tid < 100) {
    int agg = idx[b] / 6;
    float inv = 1.f / (float)(agg + 1);
    float acc = 0.f;
    for (int e = 0; e < 256; ++e) acc += pooled[e] * fw[e * 100 + tid];
    out[b * 100 + tid] = acc * inv + fb[tid];
  }
}

extern "C" void kernel_launch(void* const* d_in, const int* in_sizes, int n_in,
                              void* d_out, int out_size, void* d_ws, size_t ws_size,
                              hipStream_t stream) {
  (void)in_sizes; (void)n_in; (void)out_size;
  const float* x        = (const float*)d_in[0];
  const int*   idx      = (const int*)d_in[1];
  const float* patch_w  = (const float*)d_in[2];
  const float* patch_b  = (const float*)d_in[3];
  const float* conv_w   = (const float*)d_in[4];
  const float* conv_b   = (const float*)d_in[5];
  const float* bn_g     = (const float*)d_in[6];
  const float* bn_b     = (const float*)d_in[7];
  const float* cls_tok  = (const float*)d_in[8];
  const float* pos_emb  = (const float*)d_in[9];
  const float* Wi       = (const float*)d_in[10];
  const float* cw       = (const float*)d_in[11];
  const float* cb       = (const float*)d_in[12];
  const float* dt_bias  = (const float*)d_in[13];
  const float* A_log    = (const float*)d_in[14];
  const float* Dh       = (const float*)d_in[15];
  const float* norm_w   = (const float*)d_in[16];
  const float* Wo       = (const float*)d_in[17];
  const float* ln_g     = (const float*)d_in[18];
  const float* ln_b     = (const float*)d_in[19];
  const float* fc_w     = (const float*)d_in[20];
  const float* fc_b     = (const float*)d_in[21];
  float* out = (float*)d_out;
  float* ws = (float*)d_ws;

  // per-batch mamba overlay (floats): zxb 1,311,360 + dtr/dtb/ldb 3*16,392
  //   + xBCb 786,816 + ybuf(bf16) 524,544 + y2bf 524,544 + scb(bf16) 557,056 = 3,753,496
  // G (f32, CB*17*16384 = CB*278,528) overlays y2bf (dead during [k_ssd_g -> intra])
  auto need = [](size_t cb) {
    size_t Rsz = cb * 3753496ull;
    if (Rsz < 8388608ull) Rsz = 8388608ull;
    return (8392704ull + Rsz + 4096 + 1318912 + 524288 + 655360 + 131072 + cb * 262272ull) * 4ull;
  };
  size_t CB = 16;
  while (CB > 1 && ws_size < need(CB)) CB >>= 1;
  const int NCHUNK = (int)(16 / CB);
  const int Mc = (int)(CB * 2049);

  size_t Rsz = CB * 3753496ull;
  if (Rsz < 8388608ull) Rsz = 8388608ull;

  float* u   = ws;                 // 8,392,704
  float* R   = u + 8392704;        // Rsz
  u16*  zxb  = (u16*)R;                          // CB*1,311,360 floats
  float* dtr = R + CB * 1311360;                 // CB*16392
  float* dtb = dtr + CB * 16392;                 // CB*16392
  float* ldb = dtb + CB * 16392;                 // CB*16392
  float* afterldb = ldb + CB * 16392;
  u16*  xBCb = (u16*)afterldb;                   // CB*786,816 floats (Mc*768 u16)
  u16*  ybufb = (u16*)(afterldb + CB * 786816);  // CB*524,544 floats (Mc*512 u16)
  u16*  y2bf = (u16*)(afterldb + CB * 786816 + CB * 524544);  // CB*524,544 floats
  float* Gbuf = afterldb + CB * 786816 + CB * 524544;         // overlay on y2bf (CB*278,528 f32)
  u16*  scb = (u16*)(afterldb + CB * 786816 + CB * 524544 + CB * 524544);  // CB*557,056 floats (bf16)
  u16* fA = (u16*)R;                             // frontend overlay
  u16* fB = (u16*)(R + CB * 1572864);
  float* hln = R;                                // final overlay
  float* dtot = R + Rsz;                         // 4096
  u16*  WiT  = (u16*)(dtot + 4096);              // 1,318,912 floats
  u16*  WoT  = (u16*)((float*)WiT + 1318912);    // 524,288 floats
  u16*  wbf  = (u16*)((float*)WoT + 524288);     // 655,360 floats
  float* ppar = (float*)wbf + 655360;            // 131,072 (16*32*256)
  u16*  u_bf = (u16*)(ppar + 131072);            // CB*262,272 floats

  // ---- weight prep
  k_wconv<<<dim3((4 * 256 * 256 * 5 + 255) / 256), 256, 0, stream>>>(conv_w, wbf);
  k_wti<<<dim3((8 * 1288 * 256 + 255) / 256), 256, 0, stream>>>(Wi, WiT);
  k_wto<<<dim3((8 * 256 * 512 + 255) / 256), 256, 0, stream>>>(Wo, WoT);

  const unsigned gy = (unsigned)((Mc + 127) / 128);

  for (int bc = 0; bc < NCHUNK; ++bc) {
    const float* xc = x + (size_t)bc * CB * 8 * 12288;
    float* uc = u + (size_t)bc * CB * 2049 * 256;

    k_patchm<<<dim3(192, (unsigned)CB), 256, 0, stream>>>(xc, patch_w, patch_b, fA);
    k_convm<0><<<dim3(96, 4, (unsigned)CB), 256, 0, stream>>>(fA, wbf + 0 * 327680, conv_b + 0, bn_g + 0, bn_b + 0, fB, 12288);
    k_convm<0><<<dim3(96, 4, (unsigned)CB), 256, 0, stream>>>(fB, wbf + 1 * 327680, conv_b + 256, bn_g + 256, bn_b + 256, fA, 12288);
    {
      size_t tot = CB * 4096 * 256;
      k_mpb<<<dim3((unsigned)((tot + 255) / 256)), 256, 0, stream>>>(fA, fB, 4096, 3, tot);
    }
    k_convm<0><<<dim3(32, 4, (unsigned)CB), 256, 0, stream>>>(fB, wbf + 2 * 327680, conv_b + 512, bn_g + 512, bn_b + 512, fA, 4096);
    // conv4 with fused maxpool k=2: fA(4096) -> fB(2048)
    k_convm<1><<<dim3(32, 4, (unsigned)CB), 256, 0, stream>>>(fA, wbf + 3 * 327680, conv_b + 768, bn_g + 768, bn_b + 768, fB, 4096);
    k_asmb<<<dim3(2049, (unsigned)CB), 256, 0, stream>>>(fB, pos_emb, cls_tok, uc, u_bf);

    for (int l = 0; l < 8; ++l) {
      const u16* WiTl = WiT + (size_t)l * 1288 * 256;
      const u16* WoTl = WoT + (size_t)l * 256 * 512;
      const float* cwl  = cw + (size_t)l * 768 * 4;
      const float* cbl  = cb + (size_t)l * 768;
      const float* dtbl = dt_bias + l * 8;
      const float* all  = A_log + l * 8;
      const float* dhl  = Dh + l * 8;
      const float* nwl  = norm_w + (size_t)l * 512;

      k_gemmm<0><<<dim3(21, gy), 256, 0, stream>>>(u_bf, WiTl, zxb, dtr, nullptr, nullptr, Mc, 1288, 256);
      k_dw<<<dim3(4, 129, (unsigned)CB), 256, 0, stream>>>(zxb, dtr, cwl, cbl, dtbl, all, xBCb, dtb, ldb);
      k_ssd_g<<<dim3(17, (unsigned)CB), 256, 0, stream>>>(xBCb, Gbuf);
      k_ssd_intra<<<dim3(17, 8, (unsigned)CB), 256, 0, stream>>>(xBCb, dtb, ldb, Gbuf, ybufb, scb, dtot);
      k_ssd_scan<<<dim3((unsigned)(CB * 8 * 32)), 256, 0, stream>>>(scb, dtot, (int)(CB * 8));
      k_ssd_inter<<<dim3(17, 8, (unsigned)CB), 256, 0, stream>>>(xBCb, ldb, scb, dhl, ybufb);
      k_gaterms<<<dim3((unsigned)((Mc + 3) / 4)), 256, 0, stream>>>(ybufb, zxb, nwl, y2bf, Mc);
      k_gemmm<1><<<dim3(4, gy), 256, 0, stream>>>(y2bf, WoTl, nullptr, nullptr, uc, u_bf, Mc, 256, 512);
    }
  }

  // ---- final LN + masked pool + fc
  k_ln<<<dim3(8192), 256, 0, stream>>>(u, ln_g, ln_b, hln);
  k_pp<<<dim3(32, 16), 256, 0, stream>>>(hln, idx, ppar);
  k_fc<<<dim3(16), 256, 0, stream>>>(ppar, idx, fc_w, fc_b, out);
}

// Round 27
// 3665.520 us; speedup vs baseline: 1.1023x; 1.1023x over previous
//
#include <hip/hip_runtime.h>
#include <cstdint>
#include <cstddef>

#define EPSF 1e-5f

typedef unsigned short u16;
typedef __attribute__((ext_vector_type(8))) short short8v;
typedef __attribute__((ext_vector_type(4))) float f32x4;

static __device__ __forceinline__ u16 f2bf(float f) {
  union { float f; unsigned u; } v; v.f = f;
  unsigned r = v.u + 0x7fffu + ((v.u >> 16) & 1u);
  return (u16)(r >> 16);
}
static __device__ __forceinline__ float bf2f(u16 h) {
  union { unsigned u; float f; } v; v.u = ((unsigned)h) << 16;
  return v.f;
}

// ---------------- weight prep ----------------
__global__ void k_wconv(const float* __restrict__ src, u16* __restrict__ dst) {
  int i = blockIdx.x * 256 + threadIdx.x;
  if (i >= 4 * 256 * 256 * 5) return;
  int k = i % 5, r = i / 5;
  int ci = r & 255; r >>= 8;
  int co = r & 255; int l = r >> 8;
  dst[(((size_t)l * 256 + co) * 5 + k) * 256 + ci] = f2bf(src[i]);
}
__global__ void k_wti(const float* __restrict__ src, u16* __restrict__ dst) {
  int i = blockIdx.x * 256 + threadIdx.x;
  if (i >= 8 * 1288 * 256) return;
  int k = i & 255; int r = i >> 8;
  int n = r % 1288; int l = r / 1288;
  dst[i] = f2bf(src[((size_t)l * 256 + k) * 1288 + n]);
}
__global__ void k_wto(const float* __restrict__ src, u16* __restrict__ dst) {
  int i = blockIdx.x * 256 + threadIdx.x;
  if (i >= 8 * 256 * 512) return;
  int k = i & 511; int r = i >> 9;
  int n = r & 255; int l = r >> 8;
  dst[i] = f2bf(src[((size_t)l * 512 + k) * 256 + n]);
}

// ---------------- patch embed -> [b][L][256] bf16
__global__ __launch_bounds__(256) void k_patchm(const float* __restrict__ x, const float* __restrict__ pw,
                                                const float* __restrict__ pb, u16* __restrict__ outb) {
  __shared__ float xs[8][64];
  const int l0 = blockIdx.x * 64;
  const int b = blockIdx.y;
  const int tid = threadIdx.x;
  const float* xb = x + (size_t)b * 8 * 12288;
  for (int q = tid; q < 512; q += 256) {
    int p = q >> 6, ll = q & 63;
    xs[p][ll] = xb[(size_t)p * 12288 + l0 + ll];
  }
  __syncthreads();
  float pwr[8];
#pragma unroll
  for (int p = 0; p < 8; ++p) pwr[p] = pw[tid * 8 + p];
  const float bias = pb[tid];
  u16* ob = outb + ((size_t)b * 12288 + l0) * 256 + tid;
  for (int ll = 0; ll < 64; ++ll) {
    float acc = bias;
#pragma unroll
    for (int p = 0; p < 8; ++p) acc += xs[p][ll] * pwr[p];
    ob[(size_t)ll * 256] = f2bf(acc);
  }
}

// ---------------- MFMA conv1d (256->256, K=5 causal) + BN + ReLU, [L][C] bf16 (64-wide)
// P2==1: fused maxpool k=2 over L (output L/2 rows)
template <int P2>
__global__ __launch_bounds__(256) void k_convm(const u16* __restrict__ in, const u16* __restrict__ wbf,
                                               const float* __restrict__ cbias, const float* __restrict__ bng,
                                               const float* __restrict__ bnb, u16* __restrict__ outb, int L) {
  __shared__ u16 Xs[132 * 40];
  __shared__ u16 Ws[64 * 168];
  const int l0 = blockIdx.x * 128;
  const int co0 = blockIdx.y * 64;
  const int b = blockIdx.z;
  const int tid = threadIdx.x;
  const int w = tid >> 6, l = tid & 63;
  const int mhalf = (w >> 1) * 64, nhalf = (w & 1) * 32;
  const u16* inb = in + (size_t)b * L * 256;
  f32x4 acc[4][2] = {};
  for (int ci0 = 0; ci0 < 256; ci0 += 32) {
    __syncthreads();
    for (int q = tid; q < 528; q += 256) {
      int row = q >> 2, coff = (q & 3) * 8;
      int gl = l0 - 4 + row;
      short8v v = {};
      if (gl >= 0) v = *(const short8v*)(inb + (size_t)gl * 256 + ci0 + coff);
      *(short8v*)(Xs + row * 40 + coff) = v;
    }
    for (int q = tid; q < 1280; q += 256) {
      int co = q / 20, rem = q % 20, k = rem >> 2, coff = (rem & 3) * 8;
      *(short8v*)(Ws + co * 168 + k * 32 + coff) =
          *(const short8v*)(wbf + ((size_t)(co0 + co) * 5 + k) * 256 + ci0 + coff);
    }
    __syncthreads();
    const int koff = (l >> 4) * 8;
    const int arow = mhalf + (l & 15);
    const int bro0 = (nhalf + (l & 15)) * 168;
    const int bro1 = (nhalf + 16 + (l & 15)) * 168;
#pragma unroll
    for (int k = 0; k < 5; ++k) {
      short8v b0 = *(const short8v*)(Ws + bro0 + k * 32 + koff);
      short8v b1 = *(const short8v*)(Ws + bro1 + k * 32 + koff);
#pragma unroll
      for (int mi = 0; mi < 4; ++mi) {
        short8v a = *(const short8v*)(Xs + (arow + mi * 16 + k) * 40 + koff);
        acc[mi][0] = __builtin_amdgcn_mfma_f32_16x16x32_bf16(a, b0, acc[mi][0], 0, 0, 0);
        acc[mi][1] = __builtin_amdgcn_mfma_f32_16x16x32_bf16(a, b1, acc[mi][1], 0, 0, 0);
      }
    }
  }
  const float scn = rsqrtf(1.f + EPSF);
  if constexpr (!P2) {
    u16* outbb = outb + (size_t)b * L * 256;
#pragma unroll
    for (int ni = 0; ni < 2; ++ni) {
      int co = co0 + nhalf + ni * 16 + (l & 15);
      float alpha = bng[co] * scn;
      float beta = cbias[co] * alpha + bnb[co];
#pragma unroll
      for (int mi = 0; mi < 4; ++mi)
#pragma unroll
        for (int r = 0; r < 4; ++r) {
          int row = l0 + mhalf + mi * 16 + (l >> 4) * 4 + r;
          float v = acc[mi][ni][r] * alpha + beta;
          outbb[(size_t)row * 256 + co] = f2bf(fmaxf(v, 0.f));
        }
    }
  } else {
    const int Lo = L >> 1;
    u16* outbb = outb + (size_t)b * Lo * 256;
#pragma unroll
    for (int ni = 0; ni < 2; ++ni) {
      int co = co0 + nhalf + ni * 16 + (l & 15);
      float alpha = bng[co] * scn;
      float beta = cbias[co] * alpha + bnb[co];
#pragma unroll
      for (int mi = 0; mi < 4; ++mi) {
        int base = l0 + mhalf + mi * 16 + (l >> 4) * 4;  // even
        float vv[4];
#pragma unroll
        for (int r = 0; r < 4; ++r) vv[r] = fmaxf(acc[mi][ni][r] * alpha + beta, 0.f);
#pragma unroll
        for (int pr = 0; pr < 2; ++pr) {
          float m2 = fmaxf(vv[2 * pr], vv[2 * pr + 1]);
          int orow = (base >> 1) + pr;
          outbb[(size_t)orow * 256 + co] = f2bf(m2);
        }
      }
    }
  }
}

// ---------------- maxpool over L dim, [L][C] bf16 (k=3)
__global__ void k_mpb(const u16* __restrict__ in, u16* __restrict__ out, int Lout, int kp, size_t total) {
  size_t i = (size_t)blockIdx.x * 256 + threadIdx.x;
  if (i >= total) return;
  size_t c = i & 255;
  size_t rest = i >> 8;
  size_t lo = rest % (size_t)Lout;
  size_t b = rest / (size_t)Lout;
  const u16* p = in + (b * (size_t)Lout * kp + lo * kp) * 256 + c;
  float m = bf2f(p[0]);
  for (int j = 1; j < kp; ++j) m = fmaxf(m, bf2f(p[(size_t)j * 256]));
  out[i] = f2bf(m);
}

// ---------------- assemble u rows 0..2048 (f32 + bf16) ; row0 = cls+pos
__global__ __launch_bounds__(256) void k_asmb(const u16* __restrict__ in, const float* __restrict__ pos,
                                              const float* __restrict__ cls, float* __restrict__ uc,
                                              u16* __restrict__ ubc) {
  int t = blockIdx.x;
  int b = blockIdx.y;
  int e = threadIdx.x;
  float v;
  if (t == 0)
    v = cls[e] + pos[e];
  else
    v = bf2f(in[((size_t)b * 2048 + (t - 1)) * 256 + e]) + pos[(size_t)t * 256 + e];
  size_t o = ((size_t)b * 2049 + t) * 256 + e;
  uc[o] = v;
  ubc[o] = f2bf(v);
}

// ---------------- MFMA GEMM: A_bf[M,K] @ BT_bf[N,K]; K%32==0
// MODE 0 (in-proj): n<1280 -> zxb bf16 [M][1280]; n>=1280 -> dtr f32 [M][8]
// MODE 1 (out-proj): C[M,N] += acc (f32) and ubf bf16 copy
template <int MODE>
__global__ __launch_bounds__(256) void k_gemmm(const u16* __restrict__ A, const u16* __restrict__ BT,
                                               u16* __restrict__ OB, float* __restrict__ DT,
                                               float* __restrict__ C, u16* __restrict__ ubf,
                                               int M, int N, int K) {
  __shared__ u16 As[128 * 40];
  __shared__ u16 Bs[64 * 40];
  const int n0 = blockIdx.x * 64;
  const int m0 = blockIdx.y * 128;
  const int tid = threadIdx.x;
  const int w = tid >> 6, l = tid & 63;
  const int mhalf = (w >> 1) * 64, nhalf = (w & 1) * 32;
  f32x4 acc[4][2] = {};
  for (int k0 = 0; k0 < K; k0 += 32) {
    __syncthreads();
    for (int q = tid; q < 512; q += 256) {
      int row = q >> 2, koff = (q & 3) * 8;
      short8v v = {};
      if (m0 + row < M) v = *(const short8v*)(A + (size_t)(m0 + row) * K + k0 + koff);
      *(short8v*)(As + row * 40 + koff) = v;
    }
    {
      int row = tid >> 2, koff = (tid & 3) * 8;
      short8v v = {};
      if (n0 + row < N) v = *(const short8v*)(BT + (size_t)(n0 + row) * K + k0 + koff);
      *(short8v*)(Bs + row * 40 + koff) = v;
    }
    __syncthreads();
    const int koff = (l >> 4) * 8;
    short8v b0 = *(const short8v*)(Bs + (nhalf + (l & 15)) * 40 + koff);
    short8v b1 = *(const short8v*)(Bs + (nhalf + 16 + (l & 15)) * 40 + koff);
#pragma unroll
    for (int mi = 0; mi < 4; ++mi) {
      short8v a = *(const short8v*)(As + (mhalf + mi * 16 + (l & 15)) * 40 + koff);
      acc[mi][0] = __builtin_amdgcn_mfma_f32_16x16x32_bf16(a, b0, acc[mi][0], 0, 0, 0);
      acc[mi][1] = __builtin_amdgcn_mfma_f32_16x16x32_bf16(a, b1, acc[mi][1], 0, 0, 0);
    }
  }
#pragma unroll
  for (int mi = 0; mi < 4; ++mi)
#pragma unroll
    for (int r = 0; r < 4; ++r) {
      int m = m0 + mhalf + mi * 16 + (l >> 4) * 4 + r;
      if (m >= M) continue;
#pragma unroll
      for (int ni = 0; ni < 2; ++ni) {
        int n = n0 + nhalf + ni * 16 + (l & 15);
        if (n >= N) continue;
        float v = acc[mi][ni][r];
        if constexpr (MODE == 0) {
          if (n < 1280) OB[(size_t)m * 1280 + n] = f2bf(v);
          else DT[(size_t)m * 8 + (n - 1280)] = v;
        } else {
          float vv = C[(size_t)m * N + n] + v;
          C[(size_t)m * N + n] = vv;
          ubf[(size_t)m * N + n] = f2bf(vv);
        }
      }
    }
}

// ---------------- depthwise causal conv K=4 + silu (bf16 in/out), t-tile 16 ; bx==3: dt/ld
__global__ __launch_bounds__(256) void k_dw(const u16* __restrict__ zxb, const float* __restrict__ dtr,
                                            const float* __restrict__ cw, const float* __restrict__ cb,
                                            const float* __restrict__ dtbias, const float* __restrict__ al,
                                            u16* __restrict__ xBCb, float* __restrict__ dtb,
                                            float* __restrict__ ldb) {
  const int bx = blockIdx.x;
  const int t0 = blockIdx.y * 16;
  const int b = blockIdx.z;
  if (bx == 3) {
    int h = threadIdx.x & 7, ro = threadIdx.x >> 3;
    if (ro < 16) {
      int r = t0 + ro;
      if (r < 2049) {
        float v = dtr[((size_t)b * 2049 + r) * 8 + h] + dtbias[h];
        float d = (v > 20.f) ? v : log1pf(expf(v));
        size_t o = ((size_t)b * 2049 + r) * 8 + h;
        dtb[o] = d;
        ldb[o] = -expf(al[h]) * d;
      }
    }
    return;
  }
  int c = bx * 256 + threadIdx.x;
  const u16* col = zxb + ((size_t)b * 2049) * 1280 + 512 + c;
  float cw0 = cw[c * 4 + 0], cw1 = cw[c * 4 + 1], cw2 = cw[c * 4 + 2], cw3 = cw[c * 4 + 3];
  const float bias = cb[c];
  float w0 = 0.f, w1 = 0.f, w2 = 0.f;
  if (t0 - 3 >= 0) w0 = bf2f(col[(size_t)(t0 - 3) * 1280]);
  if (t0 - 2 >= 0) w1 = bf2f(col[(size_t)(t0 - 2) * 1280]);
  if (t0 - 1 >= 0) w2 = bf2f(col[(size_t)(t0 - 1) * 1280]);
  int tend = t0 + 16; if (tend > 2049) tend = 2049;
  u16* ob = xBCb + ((size_t)b * 2049) * 768 + c;
  for (int t = t0; t < tend; ++t) {
    float v = bf2f(col[(size_t)t * 1280]);
    float acc = bias + w0 * cw0 + w1 * cw1 + w2 * cw2 + v * cw3;
    float sig = 1.f / (1.f + expf(-acc));
    ob[(size_t)t * 768] = f2bf(acc * sig);
    w0 = w1; w1 = w2; w2 = v;
  }
}

// ================= MFMA chunked SSD (Q=128, 17 chunks over L=2049) =================
// intra+state fused per (c,h,b): G=C·Bᵀ -> Ms -> Y=Ms@X (bf16) -> XW -> Sc=XW@BT (bf16)
__global__ __launch_bounds__(256) void k_ssd_intra(const u16* __restrict__ xBCb,
                                                   const float* __restrict__ dtg,
                                                   const float* __restrict__ ldg,
                                                   u16* __restrict__ ybuf,
                                                   u16* __restrict__ sc,
                                                   float* __restrict__ dtot) {
  const int L = 2049;
  const int c = blockIdx.x, h = blockIdx.y, b = blockIdx.z;
  const int tid = threadIdx.x;
  const int w = tid >> 6, l = tid & 63;
  const int t0 = c * 128;
  int qc = L - t0; if (qc > 128) qc = 128;

  __shared__ u16 R1[128 * 136];  // Bs -> XT -> XW
  __shared__ u16 R2[128 * 136];  // Cs -> Ms -> BT
  __shared__ float dt_s[128], Lc_s[128];

  const u16* xb = xBCb + ((size_t)b * L) * 768;

  if (tid < 64) {
    int i2 = tid * 2;
    float a0 = 0.f, a1 = 0.f, d0 = 0.f, d1 = 0.f;
    if (i2 < qc) { size_t r = ((size_t)b * L + t0 + i2) * 8 + h; a0 = ldg[r]; d0 = dtg[r]; }
    if (i2 + 1 < qc) { size_t r = ((size_t)b * L + t0 + i2 + 1) * 8 + h; a1 = ldg[r]; d1 = dtg[r]; }
    dt_s[i2] = d0; dt_s[i2 + 1] = d1;
    float v = a0 + a1;
#pragma unroll
    for (int dlt = 1; dlt < 64; dlt <<= 1) {
      float t = __shfl_up(v, dlt, 64);
      if (tid >= dlt) v += t;
    }
    Lc_s[i2 + 1] = v;
    Lc_s[i2] = v - a1;
  }

  for (int q = tid; q < 2048; q += 256) {
    int row = q >> 4, off = (q & 15) * 8;
    short8v vb = {}, vc = {};
    if (row < qc) {
      const u16* src = xb + (size_t)(t0 + row) * 768;
      vb = *(const short8v*)(src + 512 + off);
      vc = *(const short8v*)(src + 640 + off);
    }
    *(short8v*)(R1 + row * 136 + off) = vb;
    *(short8v*)(R2 + row * 136 + off) = vc;
  }
  __syncthreads();  // B1

  // G = C·Bᵀ  (128×128, K=128)
  const int wm = (w >> 1) * 64, wn = (w & 1) * 64;
  f32x4 g[4][4] = {};
  const bool skipG = (wm < wn);
  if (!skipG) {
#pragma unroll
    for (int ks = 0; ks < 4; ++ks) {
      const int koff = ks * 32 + (l >> 4) * 8;
      short8v bf[4];
#pragma unroll
      for (int ni = 0; ni < 4; ++ni)
        bf[ni] = *(const short8v*)(R1 + (wn + ni * 16 + (l & 15)) * 136 + koff);
#pragma unroll
      for (int mi = 0; mi < 4; ++mi) {
        short8v a = *(const short8v*)(R2 + (wm + mi * 16 + (l & 15)) * 136 + koff);
#pragma unroll
        for (int ni = 0; ni < 4; ++ni)
          g[mi][ni] = __builtin_amdgcn_mfma_f32_16x16x32_bf16(a, bf[ni], g[mi][ni], 0, 0, 0);
      }
    }
  }
  __syncthreads();  // B2

  // Ms -> R2 ; XT -> R1 rows 0..63 ; dtot
#pragma unroll
  for (int mi = 0; mi < 4; ++mi)
#pragma unroll
    for (int r = 0; r < 4; ++r) {
      int t = wm + mi * 16 + (l >> 4) * 4 + r;
      float lct = Lc_s[t];
#pragma unroll
      for (int ni = 0; ni < 4; ++ni) {
        int s = wn + ni * 16 + (l & 15);
        float v = 0.f;
        if (s <= t) v = __expf(lct - Lc_s[s]) * dt_s[s] * g[mi][ni][r];
        R2[t * 136 + s] = f2bf(v);
      }
    }
  for (int q = tid; q < 1024; q += 256) {
    int s = q >> 3, pv = (q & 7) * 8;
    short8v v = {};
    if (s < qc) v = *(const short8v*)(xb + (size_t)(t0 + s) * 768 + h * 64 + pv);
#pragma unroll
    for (int j = 0; j < 8; ++j) R1[(pv + j) * 136 + s] = (u16)v[j];
  }
  if (tid == 0) dtot[((size_t)b * 8 + h) * 17 + c] = __expf(Lc_s[qc - 1]);
  __syncthreads();  // B3

  // Y = Ms(R2) @ XT(R1)  (128×64, K=128) -> bf16
  {
    const int wmy = (w >> 1) * 64, wny = (w & 1) * 32;
    f32x4 ya[4][2] = {};
#pragma unroll
    for (int ks = 0; ks < 4; ++ks) {
      const int koff = ks * 32 + (l >> 4) * 8;
      short8v b0 = *(const short8v*)(R1 + (wny + (l & 15)) * 136 + koff);
      short8v b1 = *(const short8v*)(R1 + (wny + 16 + (l & 15)) * 136 + koff);
#pragma unroll
      for (int mi = 0; mi < 4; ++mi) {
        short8v a = *(const short8v*)(R2 + (wmy + mi * 16 + (l & 15)) * 136 + koff);
        ya[mi][0] = __builtin_amdgcn_mfma_f32_16x16x32_bf16(a, b0, ya[mi][0], 0, 0, 0);
        ya[mi][1] = __builtin_amdgcn_mfma_f32_16x16x32_bf16(a, b1, ya[mi][1], 0, 0, 0);
      }
    }
    u16* yb = ybuf + ((size_t)b * L + t0) * 512 + h * 64;
#pragma unroll
    for (int mi = 0; mi < 4; ++mi)
#pragma unroll
      for (int r = 0; r < 4; ++r) {
        int t = wmy + mi * 16 + (l >> 4) * 4 + r;
        if (t >= qc) continue;
#pragma unroll
        for (int ni = 0; ni < 2; ++ni) {
          int p = wny + ni * 16 + (l & 15);
          yb[(size_t)t * 512 + p] = f2bf(ya[mi][ni][r]);
        }
      }
  }
  __syncthreads();  // B4

  // fused state: XW in-place in R1 rows 0..63 ; BT -> R2
  {
    const float Lend = Lc_s[qc - 1];
    for (int q = tid; q < 8192; q += 256) {
      int p = q >> 7, s = q & 127;
      float w2 = __expf(Lend - Lc_s[s]) * dt_s[s];
      R1[p * 136 + s] = f2bf(bf2f(R1[p * 136 + s]) * w2);
    }
    for (int q = tid; q < 2048; q += 256) {
      int s = q >> 4, nv = (q & 15) * 8;
      short8v v = {};
      if (s < qc) v = *(const short8v*)(xb + (size_t)(t0 + s) * 768 + 512 + nv);
#pragma unroll
      for (int j = 0; j < 8; ++j) R2[(nv + j) * 136 + s] = (u16)v[j];
    }
  }
  __syncthreads();  // B5

  // Sc = XW(R1) @ BT(R2)  (64×128, K=128) -> bf16
  {
    const int wms = (w & 1) * 32, wns = (w >> 1) * 64;
    f32x4 sa[2][4] = {};
#pragma unroll
    for (int ks = 0; ks < 4; ++ks) {
      const int koff = ks * 32 + (l >> 4) * 8;
      short8v a0 = *(const short8v*)(R1 + (wms + (l & 15)) * 136 + koff);
      short8v a1 = *(const short8v*)(R1 + (wms + 16 + (l & 15)) * 136 + koff);
#pragma unroll
      for (int ni = 0; ni < 4; ++ni) {
        short8v bb = *(const short8v*)(R2 + (wns + ni * 16 + (l & 15)) * 136 + koff);
        sa[0][ni] = __builtin_amdgcn_mfma_f32_16x16x32_bf16(a0, bb, sa[0][ni], 0, 0, 0);
        sa[1][ni] = __builtin_amdgcn_mfma_f32_16x16x32_bf16(a1, bb, sa[1][ni], 0, 0, 0);
      }
    }
    u16* scp = sc + (((size_t)b * 8 + h) * 17 + c) * 8192;
#pragma unroll
    for (int mi = 0; mi < 2; ++mi)
#pragma unroll
      for (int r = 0; r < 4; ++r) {
        int p = wms + mi * 16 + (l >> 4) * 4 + r;
#pragma unroll
        for (int ni = 0; ni < 4; ++ni) {
          int n = wns + ni * 16 + (l & 15);
          scp[p * 128 + n] = f2bf(sa[mi][ni][r]);
        }
      }
  }
}

// scan over 17 chunks; sc bf16 storage, f32 register recurrence
__global__ __launch_bounds__(256) void k_ssd_scan(u16* __restrict__ sc, const float* __restrict__ dtot,
                                                  int nbh) {
  int gid = blockIdx.x * 256 + threadIdx.x;
  int bh = gid >> 13;
  if (bh >= nbh) return;
  int elem = gid & 8191;
  u16* base = sc + (size_t)bh * 17 * 8192 + elem;
  const float* dtp = dtot + (size_t)bh * 17;
  float hc = 0.f;
#pragma unroll
  for (int cc = 0; cc < 17; ++cc) {
    float D = dtp[cc];
    float v = bf2f(base[(size_t)cc * 8192]);
    base[(size_t)cc * 8192] = f2bf(hc);
    hc = hc * D + v;
  }
}

__global__ __launch_bounds__(256) void k_ssd_inter(const u16* __restrict__ xBCb,
                                                   const float* __restrict__ ldg,
                                                   const u16* __restrict__ sc,
                                                   const float* __restrict__ Dh,
                                                   u16* __restrict__ ybuf) {
  const int L = 2049;
  const int c = blockIdx.x, h = blockIdx.y, b = blockIdx.z;
  const int tid = threadIdx.x;
  const int w = tid >> 6, l = tid & 63;
  const int t0 = c * 128;
  int qc = L - t0; if (qc > 128) qc = 128;

  __shared__ u16 Cs[128 * 136];
  __shared__ u16 H0[64 * 136];
  __shared__ float Lc_s[128];

  const u16* xb = xBCb + ((size_t)b * L) * 768;

  if (tid < 64) {
    int i2 = tid * 2;
    float a0 = 0.f, a1 = 0.f;
    if (i2 < qc) a0 = ldg[((size_t)b * L + t0 + i2) * 8 + h];
    if (i2 + 1 < qc) a1 = ldg[((size_t)b * L + t0 + i2 + 1) * 8 + h];
    float v = a0 + a1;
#pragma unroll
    for (int dlt = 1; dlt < 64; dlt <<= 1) {
      float t = __shfl_up(v, dlt, 64);
      if (tid >= dlt) v += t;
    }
    Lc_s[i2 + 1] = v;
    Lc_s[i2] = v - a1;
  }
  for (int q = tid; q < 2048; q += 256) {
    int row = q >> 4, off = (q & 15) * 8;
    short8v vc = {};
    if (row < qc) vc = *(const short8v*)(xb + (size_t)(t0 + row) * 768 + 640 + off);
    *(short8v*)(Cs + row * 136 + off) = vc;
  }
  {
    const u16* hp = sc + (((size_t)b * 8 + h) * 17 + c) * 8192;
    for (int q = tid; q < 1024; q += 256) {
      int p = q >> 4, nv = (q & 15) * 8;
      *(short8v*)(H0 + p * 136 + nv) = *(const short8v*)(hp + p * 128 + nv);
    }
  }
  __syncthreads();

  const int wm = (w >> 1) * 64, wn = (w & 1) * 32;
  f32x4 acc[4][2] = {};
#pragma unroll
  for (int ks = 0; ks < 4; ++ks) {
    const int koff = ks * 32 + (l >> 4) * 8;
    short8v b0 = *(const short8v*)(H0 + (wn + (l & 15)) * 136 + koff);
    short8v b1 = *(const short8v*)(H0 + (wn + 16 + (l & 15)) * 136 + koff);
#pragma unroll
    for (int mi = 0; mi < 4; ++mi) {
      short8v a = *(const short8v*)(Cs + (wm + mi * 16 + (l & 15)) * 136 + koff);
      acc[mi][0] = __builtin_amdgcn_mfma_f32_16x16x32_bf16(a, b0, acc[mi][0], 0, 0, 0);
      acc[mi][1] = __builtin_amdgcn_mfma_f32_16x16x32_bf16(a, b1, acc[mi][1], 0, 0, 0);
    }
  }
  const float DD = Dh[h];
  u16* yb = ybuf + ((size_t)b * L + t0) * 512 + h * 64;
#pragma unroll
  for (int mi = 0; mi < 4; ++mi)
#pragma unroll
    for (int r = 0; r < 4; ++r) {
      int t = wm + mi * 16 + (l >> 4) * 4 + r;
      if (t >= qc) continue;
      float e = __expf(Lc_s[t]);
#pragma unroll
      for (int ni = 0; ni < 2; ++ni) {
        int p = wn + ni * 16 + (l & 15);
        float xs = bf2f(xb[(size_t)(t0 + t) * 768 + h * 64 + p]);
        float old = bf2f(yb[(size_t)t * 512 + p]);
        yb[(size_t)t * 512 + p] = f2bf(old + e * acc[mi][ni][r] + DD * xs);
      }
    }
}

// ---------------- y = y*silu(z); RMS-norm over 512; *norm_w ; write bf16 (y,z bf16)
__global__ __launch_bounds__(256) void k_gaterms(const u16* __restrict__ ybuf, const u16* __restrict__ zxb,
                                                 const float* __restrict__ nw, u16* __restrict__ y2,
                                                 int Mc) {
  int row = blockIdx.x * 4 + (threadIdx.x >> 6);
  if (row >= Mc) return;
  int lane = threadIdx.x & 63;
  const u16* yr = ybuf + (size_t)row * 512 + lane * 8;
  const u16* zr = zxb + (size_t)row * 1280 + lane * 8;
  short8v yv8 = *(const short8v*)yr;
  short8v zv8 = *(const short8v*)zr;
  float g[8];
  float ss = 0.f;
#pragma unroll
  for (int j = 0; j < 8; ++j) {
    float yv = bf2f((u16)yv8[j]);
    float zv = bf2f((u16)zv8[j]);
    float sig = 1.f / (1.f + expf(-zv));
    float gg = yv * zv * sig;
    g[j] = gg;
    ss += gg * gg;
  }
#pragma unroll
  for (int off = 32; off > 0; off >>= 1) ss += __shfl_xor(ss, off);
  float r = rsqrtf(ss * (1.f / 512.f) + EPSF);
#pragma unroll
  for (int j = 0; j < 8; ++j)
    y2[(size_t)row * 512 + lane * 8 + j] = f2bf(g[j] * r * nw[lane * 8 + j]);
}

// ---------------- final LayerNorm over E=256 for rows t=1..2048 (wave per row)
__global__ __launch_bounds__(256) void k_ln(const float* __restrict__ u, const float* __restrict__ g,
                                            const float* __restrict__ bb, float* __restrict__ out) {
  int rid = blockIdx.x * 4 + (threadIdx.x >> 6);
  int lane = threadIdx.x & 63;
  int b = rid >> 11;
  int t = (rid & 2047) + 1;
  const float* ur = u + ((size_t)b * 2049 + t) * 256 + lane * 4;
  float v[4];
  float s1 = 0.f, s2 = 0.f;
#pragma unroll
  for (int j = 0; j < 4; ++j) {
    v[j] = ur[j];
    s1 += v[j];
    s2 += v[j] * v[j];
  }
#pragma unroll
  for (int off = 32; off > 0; off >>= 1) {
    s1 += __shfl_xor(s1, off);
    s2 += __shfl_xor(s2, off);
  }
  float mu = s1 * (1.f / 256.f);
  float var = s2 * (1.f / 256.f) - mu * mu;
  float rs = rsqrtf(var + EPSF);
  float* orow = out + ((size_t)b * 2048 + (t - 1)) * 256 + lane * 4;
#pragma unroll
  for (int j = 0; j < 4; ++j) orow[j] = (v[j] - mu) * rs * g[lane * 4 + j] + bb[lane * 4 + j];
}

// ---------------- masked pool partials (32 chunks of 64 rows)
__global__ __launch_bounds__(256) void k_pp(const float* __restrict__ hln, const int* __restrict__ idx,
                                            float* __restrict__ part) {
  int ch = blockIdx.x;
  int b = blockIdx.y;
  int e = threadIdx.x;
  int agg = idx[b] / 6;
  int t0 = ch * 64;
  int tend = agg + 1 - t0;
  if (tend > 64) tend = 64;
  float s = 0.f;
  for (int i = 0; i < tend; ++i) s += hln[((size_t)b * 2048 + t0 + i) * 256 + e];
  part[((size_t)b * 32 + ch) * 256 + e] = s;
}

// ---------------- pooled @ fc_w + fc_b
__global__ __launch_bounds__(256) void k_fc(const float* __restrict__ part, const int* __restrict__ idx,
                                            const float* __restrict__ fw, const float* __restrict__ fb,
                                            float* __restrict__ out) {
  __shared__ float pooled[256];
  int b = blockIdx.x;
  int tid = threadIdx.x;
  float s = 0.f;
#pragma unroll
  for (int ch = 0; ch < 32; ++ch) s += part[((size_t)b * 32 + ch) * 256 + tid];
  pooled[tid] = s;
  __syncthreads();
  if (tid < 100) {
    int agg = idx[b] / 6;
    float inv = 1.f / (float)(agg + 1);
    float acc = 0.f;
    for (int e = 0; e < 256; ++e) acc += pooled[e] * fw[e * 100 + tid];
    out[b * 100 + tid] = acc * inv + fb[tid];
  }
}

extern "C" void kernel_launch(void* const* d_in, const int* in_sizes, int n_in,
                              void* d_out, int out_size, void* d_ws, size_t ws_size,
                              hipStream_t stream) {
  (void)in_sizes; (void)n_in; (void)out_size;
  const float* x        = (const float*)d_in[0];
  const int*   idx      = (const int*)d_in[1];
  const float* patch_w  = (const float*)d_in[2];
  const float* patch_b  = (const float*)d_in[3];
  const float* conv_w   = (const float*)d_in[4];
  const float* conv_b   = (const float*)d_in[5];
  const float* bn_g     = (const float*)d_in[6];
  const float* bn_b     = (const float*)d_in[7];
  const float* cls_tok  = (const float*)d_in[8];
  const float* pos_emb  = (const float*)d_in[9];
  const float* Wi       = (const float*)d_in[10];
  const float* cw       = (const float*)d_in[11];
  const float* cb       = (const float*)d_in[12];
  const float* dt_bias  = (const float*)d_in[13];
  const float* A_log    = (const float*)d_in[14];
  const float* Dh       = (const float*)d_in[15];
  const float* norm_w   = (const float*)d_in[16];
  const float* Wo       = (const float*)d_in[17];
  const float* ln_g     = (const float*)d_in[18];
  const float* ln_b     = (const float*)d_in[19];
  const float* fc_w     = (const float*)d_in[20];
  const float* fc_b     = (const float*)d_in[21];
  float* out = (float*)d_out;
  float* ws = (float*)d_ws;

  // per-batch mamba overlay (floats): zxb 1,311,360 + dtr/dtb/ldb 3*16,392
  //   + xBCb 786,816 + ybuf(bf16) 524,544 + y2bf 524,544 + scb(bf16) 557,056 = 3,753,496
  auto need = [](size_t cb) {
    size_t Rsz = cb * 3753496ull;
    if (Rsz < 8388608ull) Rsz = 8388608ull;
    return (8392704ull + Rsz + 4096 + 1318912 + 524288 + 655360 + 131072 + cb * 262272ull) * 4ull;
  };
  size_t CB = 16;
  while (CB > 1 && ws_size < need(CB)) CB >>= 1;
  const int NCHUNK = (int)(16 / CB);
  const int Mc = (int)(CB * 2049);

  size_t Rsz = CB * 3753496ull;
  if (Rsz < 8388608ull) Rsz = 8388608ull;

  float* u   = ws;                 // 8,392,704
  float* R   = u + 8392704;        // Rsz
  u16*  zxb  = (u16*)R;                          // CB*1,311,360 floats
  float* dtr = R + CB * 1311360;                 // CB*16392
  float* dtb = dtr + CB * 16392;                 // CB*16392
  float* ldb = dtb + CB * 16392;                 // CB*16392
  float* afterldb = ldb + CB * 16392;
  u16*  xBCb = (u16*)afterldb;                   // CB*786,816 floats (Mc*768 u16)
  u16*  ybufb = (u16*)(afterldb + CB * 786816);  // CB*524,544 floats (Mc*512 u16)
  u16*  y2bf = (u16*)(afterldb + CB * 786816 + CB * 524544);  // CB*524,544 floats
  u16*  scb = (u16*)(afterldb + CB * 786816 + CB * 524544 + CB * 524544);  // CB*557,056 floats (bf16)
  u16* fA = (u16*)R;                             // frontend overlay
  u16* fB = (u16*)(R + CB * 1572864);
  float* hln = R;                                // final overlay
  float* dtot = R + Rsz;                         // 4096
  u16*  WiT  = (u16*)(dtot + 4096);              // 1,318,912 floats
  u16*  WoT  = (u16*)((float*)WiT + 1318912);    // 524,288 floats
  u16*  wbf  = (u16*)((float*)WoT + 524288);     // 655,360 floats
  float* ppar = (float*)wbf + 655360;            // 131,072 (16*32*256)
  u16*  u_bf = (u16*)(ppar + 131072);            // CB*262,272 floats

  // ---- weight prep
  k_wconv<<<dim3((4 * 256 * 256 * 5 + 255) / 256), 256, 0, stream>>>(conv_w, wbf);
  k_wti<<<dim3((8 * 1288 * 256 + 255) / 256), 256, 0, stream>>>(Wi, WiT);
  k_wto<<<dim3((8 * 256 * 512 + 255) / 256), 256, 0, stream>>>(Wo, WoT);

  const unsigned gy = (unsigned)((Mc + 127) / 128);

  for (int bc = 0; bc < NCHUNK; ++bc) {
    const float* xc = x + (size_t)bc * CB * 8 * 12288;
    float* uc = u + (size_t)bc * CB * 2049 * 256;

    k_patchm<<<dim3(192, (unsigned)CB), 256, 0, stream>>>(xc, patch_w, patch_b, fA);
    k_convm<0><<<dim3(96, 4, (unsigned)CB), 256, 0, stream>>>(fA, wbf + 0 * 327680, conv_b + 0, bn_g + 0, bn_b + 0, fB, 12288);
    k_convm<0><<<dim3(96, 4, (unsigned)CB), 256, 0, stream>>>(fB, wbf + 1 * 327680, conv_b + 256, bn_g + 256, bn_b + 256, fA, 12288);
    {
      size_t tot = CB * 4096 * 256;
      k_mpb<<<dim3((unsigned)((tot + 255) / 256)), 256, 0, stream>>>(fA, fB, 4096, 3, tot);
    }
    k_convm<0><<<dim3(32, 4, (unsigned)CB), 256, 0, stream>>>(fB, wbf + 2 * 327680, conv_b + 512, bn_g + 512, bn_b + 512, fA, 4096);
    // conv4 with fused maxpool k=2: fA(4096) -> fB(2048)
    k_convm<1><<<dim3(32, 4, (unsigned)CB), 256, 0, stream>>>(fA, wbf + 3 * 327680, conv_b + 768, bn_g + 768, bn_b + 768, fB, 4096);
    k_asmb<<<dim3(2049, (unsigned)CB), 256, 0, stream>>>(fB, pos_emb, cls_tok, uc, u_bf);

    for (int l = 0; l < 8; ++l) {
      const u16* WiTl = WiT + (size_t)l * 1288 * 256;
      const u16* WoTl = WoT + (size_t)l * 256 * 512;
      const float* cwl  = cw + (size_t)l * 768 * 4;
      const float* cbl  = cb + (size_t)l * 768;
      const float* dtbl = dt_bias + l * 8;
      const float* all  = A_log + l * 8;
      const float* dhl  = Dh + l * 8;
      const float* nwl  = norm_w + (size_t)l * 512;

      k_gemmm<0><<<dim3(21, gy), 256, 0, stream>>>(u_bf, WiTl, zxb, dtr, nullptr, nullptr, Mc, 1288, 256);
      k_dw<<<dim3(4, 129, (unsigned)CB), 256, 0, stream>>>(zxb, dtr, cwl, cbl, dtbl, all, xBCb, dtb, ldb);
      k_ssd_intra<<<dim3(17, 8, (unsigned)CB), 256, 0, stream>>>(xBCb, dtb, ldb, ybufb, scb, dtot);
      k_ssd_scan<<<dim3((unsigned)(CB * 8 * 32)), 256, 0, stream>>>(scb, dtot, (int)(CB * 8));
      k_ssd_inter<<<dim3(17, 8, (unsigned)CB), 256, 0, stream>>>(xBCb, ldb, scb, dhl, ybufb);
      k_gaterms<<<dim3((unsigned)((Mc + 3) / 4)), 256, 0, stream>>>(ybufb, zxb, nwl, y2bf, Mc);
      k_gemmm<1><<<dim3(4, gy), 256, 0, stream>>>(y2bf, WoTl, nullptr, nullptr, uc, u_bf, Mc, 256, 512);
    }
  }

  // ---- final LN + masked pool + fc
  k_ln<<<dim3(8192), 256, 0, stream>>>(u, ln_g, ln_b, hln);
  k_pp<<<dim3(32, 16), 256, 0, stream>>>(hln, idx, ppar);
  k_fc<<<dim3(16), 256, 0, stream>>>(ppar, idx, fc_w, fc_b, out);
}